// Round 15
// baseline (290.268 us; speedup 1.0000x reference)
//
#include <hip/hip_runtime.h>

// N=100000 nodes, M=800000 edges, F_IN=64, F_E=16, H=64, T_NODE=2, T_EDGE=3.
// score == softmax over singleton axis == 1.0 exactly, so h3/h4/num are dead:
//   out[n] = h1[n] + sum_{e: dst=n} ( h2[src_e] + ef_e . W5[t_e] + b5[t_e] )
//
// R22: K2 phase 1 = single-dst 16-deep batch. R19/R21's pair-8 had a
// program-order-serialized second chunk for deg>8 (44% of dsts) -- a second
// full latency chain whose addresses never depended on the first chunk.
// R20's pair-16 fix cost 28 VGPRs (occ 45->30%, regression). Single-dst-16
// keeps the exact register footprint of pair-8 (r[16] in SGPRs, hv/ev = 32
// VGPRs, 32 loads in flight) while deleting the serial chunk; deg<16 slots
// are masked to row 0 (L1 broadcast, no HBM traffic).
//  K0: zero-init + W1/W2 -> wtb transpose (stream-orders wtb before K1).
//  K1: even blocks = slim gemm (B from global wtb); odd = scatter.
//  K2: gather (16-deep single-dst) + fused MFMA matvec, bf16 sHb.

#define CAP 16
#define OVF_CAP 32768

typedef __attribute__((ext_vector_type(8))) short short8;
typedef __attribute__((ext_vector_type(4))) float f32x4;

__device__ __forceinline__ float b2f(unsigned short u) {
    union { unsigned v; float f; } x; x.v = ((unsigned)u) << 16; return x.f;
}
__device__ __forceinline__ unsigned short f2b(float f) {
    union { float f; unsigned v; } x; x.f = f;
    unsigned u = x.v;
    unsigned r = (u + 0x7FFFu + ((u >> 16) & 1u)) >> 16;
    return (unsigned short)r;
}

// ---------------- K0: zero cnt block + one-shot weight transpose ------------
__global__ __launch_bounds__(256) void k0_init(
    int* __restrict__ zeroBase, int nZero,
    const float* __restrict__ W1, const float* __restrict__ W2,
    unsigned short* __restrict__ wtb)
{
    int idx = blockIdx.x * 256 + threadIdx.x;
    if (idx < nZero) zeroBase[idx] = 0;
    if (idx < 16384) {
        int mm = idx >> 12;
        int r  = idx & 4095;
        int n  = r >> 6;
        int k  = r & 63;
        const float* src = ((mm < 2) ? W1 : W2) + (mm & 1) * 4096;
        wtb[mm * 4096 + n * 64 + k] = f2b(src[k * 64 + n]);
    }
}

// ---------------- K1: slim gemm (even blocks) || scatter (odd blocks) -------
__global__ __launch_bounds__(256) void k1_fused(
    const float* __restrict__ x, const int* __restrict__ nt,
    const unsigned short* __restrict__ wtb,
    const float* __restrict__ b1, const float* __restrict__ b2,
    const int* __restrict__ esrc, const int* __restrict__ edst,
    const int* __restrict__ etype,
    int* __restrict__ cnt32, int* __restrict__ ovfCnt,
    int4* __restrict__ ovf, int2* __restrict__ rec,
    float* __restrict__ out, unsigned short* __restrict__ h2b,
    int N, int M)
{
    // 72 = 64 + 8 pad: row stride 144 B -> 2-way bank alias (free)
    __shared__ __align__(16) unsigned short sx[128 * 72];     // 18 KB
    __shared__ int snt[128];

    int tid = threadIdx.x;

    if (blockIdx.x & 1) {
        // ---------------- scatter path: 1024 edges/block ---------------------
        int e0 = (blockIdx.x >> 1) * 1024 + tid;
        int dd[4], ssrc[4], tty[4];
        bool v[4];
#pragma unroll
        for (int j = 0; j < 4; ++j) {
            int e = e0 + j * 256;
            v[j] = e < M;
            int ec = v[j] ? e : 0;
            dd[j]   = edst[ec];
            ssrc[j] = esrc[ec];
            tty[j]  = etype[ec];
        }
        int pos[4];
#pragma unroll
        for (int j = 0; j < 4; ++j)
            if (v[j]) pos[j] = atomicAdd(&cnt32[dd[j]], 1);
#pragma unroll
        for (int j = 0; j < 4; ++j) {
            if (!v[j]) continue;
            int packed = ssrc[j] | (tty[j] << 20);
            int e = e0 + j * 256;
            if (pos[j] < CAP) {
                rec[dd[j] * CAP + pos[j]] = make_int2(packed, e);
            } else {
                int slot = atomicAdd(ovfCnt, 1);
                if (slot < OVF_CAP) ovf[slot] = make_int4(packed, e, dd[j], 0);
            }
        }
        return;
    }

    // ---------------- gemm path (B from global wtb) -------------------------
    int rowbase = (blockIdx.x >> 1) * 128;

    if (tid < 128) {
        int r = rowbase + tid;
        snt[tid] = (r < N) ? nt[r] : 0;
    }

    // stage x tile (contiguous rows, no perm)
    int fr = (tid & 15) * 4;
    int ir = tid >> 4;
#pragma unroll
    for (int it = 0; it < 8; ++it) {
        int i = it * 16 + ir;
        int r = rowbase + i;
        float4 v = make_float4(0.f, 0.f, 0.f, 0.f);
        if (r < N) v = *(const float4*)&x[(size_t)r * 64 + fr];
        ushort4 p;
        p.x = f2b(v.x); p.y = f2b(v.y); p.z = f2b(v.z); p.w = f2b(v.w);
        *(ushort4*)&sx[i * 72 + fr] = p;
    }
    __syncthreads();

    int lane = tid & 63;
    int wid  = tid >> 6;
    int q    = lane >> 4;
    int cc   = lane & 15;
    int m0   = wid * 32;

    f32x4 acc[4][2][4];   // [mat][s][t]
#pragma unroll
    for (int mm = 0; mm < 4; ++mm)
#pragma unroll
        for (int s = 0; s < 2; ++s)
#pragma unroll
            for (int t = 0; t < 4; ++t)
                acc[mm][s][t] = (f32x4){0.f, 0.f, 0.f, 0.f};

#pragma unroll
    for (int k0 = 0; k0 < 64; k0 += 32) {
        int ko = k0 + q * 8;
        short8 af0 = *(short8*)&sx[(m0 + cc) * 72 + ko];
        short8 af1 = *(short8*)&sx[(m0 + 16 + cc) * 72 + ko];
#pragma unroll
        for (int mm = 0; mm < 4; ++mm)
#pragma unroll
            for (int t = 0; t < 4; ++t) {
                // wtb[mm][n][k] == f2b(Wm[k][n]); 16B aligned (ko % 8 == 0)
                short8 bf = *(const short8*)
                    &wtb[mm * 4096 + (t * 16 + cc) * 64 + ko];
                acc[mm][0][t] = __builtin_amdgcn_mfma_f32_16x16x32_bf16(
                    af0, bf, acc[mm][0][t], 0, 0, 0);
                acc[mm][1][t] = __builtin_amdgcn_mfma_f32_16x16x32_bf16(
                    af1, bf, acc[mm][1][t], 0, 0, 0);
            }
    }

    float b1v[2][4], b2v[2][4];
#pragma unroll
    for (int ty = 0; ty < 2; ++ty)
#pragma unroll
        for (int t = 0; t < 4; ++t) {
            b1v[ty][t] = b1[ty * 64 + t * 16 + cc];
            b2v[ty][t] = b2[ty * 64 + t * 16 + cc];
        }

    // C/D layout: col = lane&15, row = quad*4 + reg
#pragma unroll
    for (int s = 0; s < 2; ++s)
#pragma unroll
        for (int reg = 0; reg < 4; ++reg) {
            int rl_ = m0 + s * 16 + q * 4 + reg;
            int r = rowbase + rl_;
            if (r < N) {
                int ty = snt[rl_];
#pragma unroll
                for (int t = 0; t < 4; ++t) {
                    float v1 = (ty ? acc[1][s][t][reg] : acc[0][s][t][reg])
                               + b1v[ty][t];
                    float v2 = (ty ? acc[3][s][t][reg] : acc[2][s][t][reg])
                               + b2v[ty][t];
                    out[(size_t)r * 64 + t * 16 + cc] = v1;
                    h2b[(size_t)r * 64 + t * 16 + cc] = f2b(v2);
                }
            }
        }
}

// ---------------- K2: gather + fused MFMA matvec (32 dsts / block) ----------
// Phase 1 (per wave, 8 dsts, 16-deep single-dst): all 16 rec slots load up
//   front (wave-uniform -> s_load; slots >= cnt are garbage and get masked
//   to row 0 before address use), all 32 gathers issue, one predicated
//   accumulate. No serial second chunk; register footprint == pair-8.
// Phase 2: C[32x64] = sa * swt (B deduped: swt[h][k&63], 52 real cols);
//   epilogue adds C + b2f(sHb) to out; plain RMW unless row has cnt>CAP.
__global__ __launch_bounds__(256) void k2_gather_mm(
    const float* __restrict__ ef, const int2* __restrict__ rec,
    const int* __restrict__ cnt32,
    const float* __restrict__ W5, const float* __restrict__ b5,
    const int4* __restrict__ ovf, const int* __restrict__ ovfCnt,
    const unsigned short* __restrict__ h2b, float* __restrict__ out,
    int N, int gatherBlocks, int ovfBlocks)
{
    __shared__ __align__(16) unsigned short sa[32 * 136];    // 8.5 KB  A tile
    __shared__ __align__(16) unsigned short swt[64 * 72];    // 9 KB    B tile
    __shared__ __align__(16) unsigned short sHb[32 * 66];    // 4.125KB accH bf16
    __shared__ int sCnt[32];

    int tid = threadIdx.x;
    int lane = tid & 63;
    int wid = tid >> 6;

    if (blockIdx.x >= (unsigned)gatherBlocks) {
        // ---- overflow fixup: grid-stride waves over ovf list (rare) ----
        int novf = min(*ovfCnt, OVF_CAP);
        int gw = (blockIdx.x - gatherBlocks) * 4 + wid;
        int nw = ovfBlocks * 4;
        for (int ri = gw; ri < novf; ri += nw) {
            int4 o = ovf[ri];
            int s = o.x & 0xFFFFF;
            int t = (unsigned)o.x >> 20;
            float acc = b5[t * 64 + lane] + b2f(h2b[((size_t)s << 6) | lane]);
#pragma unroll
            for (int f = 0; f < 16; ++f)
                acc = fmaf(ef[(size_t)o.y * 16 + f],
                           W5[(t * 16 + f) * 64 + lane], acc);
            unsafeAtomicAdd(&out[(size_t)o.z * 64 + lane], acc);
        }
        return;
    }

    // ---- stage B: [W5;b5] -> swt[h][j], j<52 (j==51 -> 0; R14 lesson) ----
#pragma unroll
    for (int k = 0; k < 13; ++k) {
        int idx = tid + k * 256;                  // 3328 = 52*64 exact
        int j = idx >> 6;
        int h = idx & 63;
        float wv = 0.f;
        if (j < 48)      wv = W5[j * 64 + h];
        else if (j < 51) wv = b5[(j - 48) * 64 + h];
        swt[h * 72 + j] = f2b(wv);
    }
    {
        ushort4 z; z.x = 0; z.y = 0; z.z = 0; z.w = 0;
        // B cols 52..63: 64 rows x 3 ushort4 = 192 tasks
        if (tid < 192) {
            int h = tid / 3;
            int sp = (tid - h * 3) * 4;
            *(ushort4*)&swt[h * 72 + 52 + sp] = z;
        }
        // A cols 52..63 and 116..127: 32 rows x 6 ushort4 = 192 tasks
        if (tid < 192) {
            int row = tid / 6;
            int w6 = tid - row * 6;
            int sp = (w6 < 3) ? (52 + w6 * 4) : (116 + (w6 - 3) * 4);
            *(ushort4*)&sa[row * 136 + sp] = z;
        }
    }

    // ---- phase 1: 8 dsts per wave, 16-deep single-dst batches ----
    int myt = (lane < 48) ? (lane >> 4) : (lane - 48);
    unsigned myf = lane & 15;
    bool fl = lane < 48;
    int wbase = blockIdx.x * 32 + wid * 8;

    int cnts[8];
#pragma unroll
    for (int g = 0; g < 8; ++g) {
        int d = wbase + g;
        cnts[g] = (d < N) ? cnt32[d] : 0;
    }
    if (lane == 0) {
#pragma unroll
        for (int g = 0; g < 8; ++g) sCnt[wid * 8 + g] = cnts[g];
    }

#pragma unroll 1
    for (int g = 0; g < 8; ++g) {
        int d = wbase + g;
        int dg = min(cnts[g], CAP);
        unsigned base = (unsigned)(d < N ? d : 0) * CAP;

        // all 16 rec slots (wave-uniform -> scalar loads); slots >= cnt
        // hold garbage but are never used un-masked
        int2 r[16];
#pragma unroll
        for (int j = 0; j < 16; ++j) r[j] = rec[base + j];

        // all 32 gathers issue before any accumulate (masked -> row 0)
        float hv[16], ev[16];
#pragma unroll
        for (int j = 0; j < 16; ++j) {
            bool ok = j < dg;
            unsigned s = ok ? ((unsigned)r[j].x & 0xFFFFFu) : 0u;
            unsigned e = ok ? (unsigned)r[j].y : 0u;
            hv[j] = b2f(h2b[((size_t)s << 6) | (unsigned)lane]);
            ev[j] = ef[(e << 4) | myf];
        }

        float accH = 0.f, accS = 0.f;
#pragma unroll
        for (int j = 0; j < 16; ++j) {
            bool ok = j < dg;
            int t = (int)((unsigned)r[j].x >> 20);
            accH += ok ? hv[j] : 0.f;
            float v = fl ? ev[j] : 1.0f;
            accS += (ok && t == myt) ? v : 0.f;
        }

        int wd = wid * 8 + g;
        if (lane < 52) {
            unsigned short hi = f2b(accS);
            sa[wd * 136 + lane] = hi;
            sa[wd * 136 + 64 + lane] = f2b(accS - b2f(hi));
        }
        sHb[wd * 66 + lane] = f2b(accH);
    }
    __syncthreads();

    // ---- phase 2: C[32x64] via MFMA; wave -> row-tile (wid&1),
    //      col-tiles {wid>>1, (wid>>1)+2}; B fragment reads ko&63 ----
    int q  = lane >> 4;
    int cc = lane & 15;
    int s  = wid & 1;
    int t0 = wid >> 1;

    f32x4 acc0 = (f32x4){0.f, 0.f, 0.f, 0.f};
    f32x4 acc1 = (f32x4){0.f, 0.f, 0.f, 0.f};
#pragma unroll
    for (int k0 = 0; k0 < 128; k0 += 32) {
        int ko = k0 + q * 8;
        int kb = ko & 63;
        short8 af = *(short8*)&sa[(s * 16 + cc) * 136 + ko];
        short8 bf0 = *(short8*)&swt[(t0 * 16 + cc) * 72 + kb];
        short8 bf1 = *(short8*)&swt[((t0 + 2) * 16 + cc) * 72 + kb];
        acc0 = __builtin_amdgcn_mfma_f32_16x16x32_bf16(af, bf0, acc0, 0, 0, 0);
        acc1 = __builtin_amdgcn_mfma_f32_16x16x32_bf16(af, bf1, acc1, 0, 0, 0);
    }

    // C/D layout: col = lane&15, row = quad*4 + reg
#pragma unroll
    for (int reg = 0; reg < 4; ++reg) {
        int rl = s * 16 + q * 4 + reg;
        int d = blockIdx.x * 32 + rl;
        if (d < N) {
            int c0 = t0 * 16 + cc;
            int c1 = (t0 + 2) * 16 + cc;
            float v0 = acc0[reg] + b2f(sHb[rl * 66 + c0]);
            float v1 = acc1[reg] + b2f(sHb[rl * 66 + c1]);
            float* p0 = &out[(size_t)d * 64 + c0];
            float* p1 = &out[(size_t)d * 64 + c1];
            if (sCnt[rl] > CAP) {      // row shared with ovf fixup -> atomic
                unsafeAtomicAdd(p0, v0);
                unsafeAtomicAdd(p1, v1);
            } else {                   // sole writer -> plain RMW
                *p0 += v0;
                *p1 += v1;
            }
        }
    }
}

extern "C" void kernel_launch(void* const* d_in, const int* in_sizes, int n_in,
                              void* d_out, int out_size, void* d_ws, size_t ws_size,
                              hipStream_t stream) {
    const float* x  = (const float*)d_in[0];
    const float* ef = (const float*)d_in[1];
    const int* nt   = (const int*)d_in[2];
    const int* es   = (const int*)d_in[3];
    const int* ed   = (const int*)d_in[4];
    const int* et   = (const int*)d_in[5];
    const float* W1 = (const float*)d_in[6];
    const float* b1 = (const float*)d_in[7];
    const float* W2 = (const float*)d_in[8];
    const float* b2 = (const float*)d_in[9];
    // d_in[10..13] = W3,b3,W4,b4 dead (score == 1.0)
    const float* W5 = (const float*)d_in[14];
    const float* b5 = (const float*)d_in[15];

    int N = in_sizes[2];
    int M = in_sizes[3];

    char* w = (char*)d_ws;
    size_t off = 0;
    unsigned short* h2b = (unsigned short*)(w + off); off += (size_t)N * 64 * 2;  // 12.8 MB
    off = (off + 255) & ~(size_t)255;
    int2* rec = (int2*)(w + off); off += (size_t)N * CAP * 8;                     // 12.8 MB
    off = (off + 255) & ~(size_t)255;
    int4* ovf = (int4*)(w + off); off += (size_t)OVF_CAP * 16;                    // 0.5 MB
    off = (off + 255) & ~(size_t)255;
    unsigned short* wtb = (unsigned short*)(w + off); off += 4 * 4096 * 2;        // 32 KB
    off = (off + 255) & ~(size_t)255;
    // zero block: [ovfCnt:1 int][pad->64 B][cnt32: N ints]
    int* ovfCnt = (int*)(w + off);
    int* cnt32  = (int*)(w + off + 64);
    int nZero = 16 + N;                      // ints: ovfCnt+pad + cnt32

    float* out = (float*)d_out;

    int initBlocks = (nZero + 255) / 256;    // 391 (also covers 16384 wtb)
    k0_init<<<initBlocks, 256, 0, stream>>>(ovfCnt, nZero, W1, W2, wtb);

    int gemmBlocks    = (N + 127) / 128;     // 782
    int scatterBlocks = (M + 1023) / 1024;   // 782
    int gb1 = 2 * max(gemmBlocks, scatterBlocks);
    k1_fused<<<gb1, 256, 0, stream>>>(
        x, nt, wtb, b1, b2, es, ed, et,
        cnt32, ovfCnt, ovf, rec, out, h2b, N, M);

    int gatherBlocks = (N + 31) / 32;        // 3125
    int ovfBlocks = 32;
    k2_gather_mm<<<gatherBlocks + ovfBlocks, 256, 0, stream>>>(
        ef, rec, cnt32, W5, b5, ovf, ovfCnt, h2b, out,
        N, gatherBlocks, ovfBlocks);
}

// Round 16
// 282.463 us; speedup vs baseline: 1.0276x; 1.0276x over previous
//
#include <hip/hip_runtime.h>

// N=100000 nodes, M=800000 edges, F_IN=64, F_E=16, H=64, T_NODE=2, T_EDGE=3.
// score == softmax over singleton axis == 1.0 exactly, so h3/h4/num are dead:
//   out[n] = h1[n] + sum_{e: dst=n} ( h2[src_e] + ef_e . W5[t_e] + b5[t_e] )
//
// R23 = R21 (best, 279.1us; pair-8 phase 1 is the proven optimum -- R20/R22
// depth variants both regressed via VGPR/occupancy) + one orthogonal lever:
// K2's swt LDS tile deleted. [W5;b5] is precomputed ONCE by K0 into a global
// bf16 table wtb5[64 h][64 k] (cols 52..63 zero); K2 phase 2 reads B
// fragments straight from L2 (R18's proven pattern for 1x-reuse operands).
// K2 LDS 22.5->13.1KB, per-block staging (3328 ops x 3157 blocks) gone.
//  K0: zero-init + W1/W2 -> wtb + [W5;b5] -> wtb5.
//  K1: even blocks = slim gemm (B from global wtb); odd = scatter.
//  K2: gather (8-deep pairs) + fused MFMA matvec, bf16 sHb, B from wtb5.

#define CAP 16
#define OVF_CAP 32768

typedef __attribute__((ext_vector_type(8))) short short8;
typedef __attribute__((ext_vector_type(4))) float f32x4;

__device__ __forceinline__ float b2f(unsigned short u) {
    union { unsigned v; float f; } x; x.v = ((unsigned)u) << 16; return x.f;
}
__device__ __forceinline__ unsigned short f2b(float f) {
    union { float f; unsigned v; } x; x.f = f;
    unsigned u = x.v;
    unsigned r = (u + 0x7FFFu + ((u >> 16) & 1u)) >> 16;
    return (unsigned short)r;
}

// ---------------- K0: zero cnt block + one-shot weight tables ---------------
__global__ __launch_bounds__(256) void k0_init(
    int* __restrict__ zeroBase, int nZero,
    const float* __restrict__ W1, const float* __restrict__ W2,
    const float* __restrict__ W5, const float* __restrict__ b5,
    unsigned short* __restrict__ wtb, unsigned short* __restrict__ wtb5)
{
    int idx = blockIdx.x * 256 + threadIdx.x;
    if (idx < nZero) zeroBase[idx] = 0;
    if (idx < 16384) {
        int mm = idx >> 12;
        int r  = idx & 4095;
        int n  = r >> 6;
        int k  = r & 63;
        const float* src = ((mm < 2) ? W1 : W2) + (mm & 1) * 4096;
        wtb[mm * 4096 + n * 64 + k] = f2b(src[k * 64 + n]);
    }
    if (idx < 4096) {
        int h = idx >> 6;                 // 0..63 output col
        int j = idx & 63;                 // 0..63 K index
        float wv = 0.f;
        if (j < 48)      wv = W5[j * 64 + h];
        else if (j < 51) wv = b5[(j - 48) * 64 + h];
        wtb5[h * 64 + j] = f2b(wv);       // cols 51..63 zero
    }
}

// ---------------- K1: slim gemm (even blocks) || scatter (odd blocks) -------
__global__ __launch_bounds__(256) void k1_fused(
    const float* __restrict__ x, const int* __restrict__ nt,
    const unsigned short* __restrict__ wtb,
    const float* __restrict__ b1, const float* __restrict__ b2,
    const int* __restrict__ esrc, const int* __restrict__ edst,
    const int* __restrict__ etype,
    int* __restrict__ cnt32, int* __restrict__ ovfCnt,
    int4* __restrict__ ovf, int2* __restrict__ rec,
    float* __restrict__ out, unsigned short* __restrict__ h2b,
    int N, int M)
{
    // 72 = 64 + 8 pad: row stride 144 B -> 2-way bank alias (free)
    __shared__ __align__(16) unsigned short sx[128 * 72];     // 18 KB
    __shared__ int snt[128];

    int tid = threadIdx.x;

    if (blockIdx.x & 1) {
        // ---------------- scatter path: 1024 edges/block ---------------------
        int e0 = (blockIdx.x >> 1) * 1024 + tid;
        int dd[4], ssrc[4], tty[4];
        bool v[4];
#pragma unroll
        for (int j = 0; j < 4; ++j) {
            int e = e0 + j * 256;
            v[j] = e < M;
            int ec = v[j] ? e : 0;
            dd[j]   = edst[ec];
            ssrc[j] = esrc[ec];
            tty[j]  = etype[ec];
        }
        int pos[4];
#pragma unroll
        for (int j = 0; j < 4; ++j)
            if (v[j]) pos[j] = atomicAdd(&cnt32[dd[j]], 1);
#pragma unroll
        for (int j = 0; j < 4; ++j) {
            if (!v[j]) continue;
            int packed = ssrc[j] | (tty[j] << 20);
            int e = e0 + j * 256;
            if (pos[j] < CAP) {
                rec[dd[j] * CAP + pos[j]] = make_int2(packed, e);
            } else {
                int slot = atomicAdd(ovfCnt, 1);
                if (slot < OVF_CAP) ovf[slot] = make_int4(packed, e, dd[j], 0);
            }
        }
        return;
    }

    // ---------------- gemm path (B from global wtb) -------------------------
    int rowbase = (blockIdx.x >> 1) * 128;

    if (tid < 128) {
        int r = rowbase + tid;
        snt[tid] = (r < N) ? nt[r] : 0;
    }

    // stage x tile (contiguous rows, no perm)
    int fr = (tid & 15) * 4;
    int ir = tid >> 4;
#pragma unroll
    for (int it = 0; it < 8; ++it) {
        int i = it * 16 + ir;
        int r = rowbase + i;
        float4 v = make_float4(0.f, 0.f, 0.f, 0.f);
        if (r < N) v = *(const float4*)&x[(size_t)r * 64 + fr];
        ushort4 p;
        p.x = f2b(v.x); p.y = f2b(v.y); p.z = f2b(v.z); p.w = f2b(v.w);
        *(ushort4*)&sx[i * 72 + fr] = p;
    }
    __syncthreads();

    int lane = tid & 63;
    int wid  = tid >> 6;
    int q    = lane >> 4;
    int cc   = lane & 15;
    int m0   = wid * 32;

    f32x4 acc[4][2][4];   // [mat][s][t]
#pragma unroll
    for (int mm = 0; mm < 4; ++mm)
#pragma unroll
        for (int s = 0; s < 2; ++s)
#pragma unroll
            for (int t = 0; t < 4; ++t)
                acc[mm][s][t] = (f32x4){0.f, 0.f, 0.f, 0.f};

#pragma unroll
    for (int k0 = 0; k0 < 64; k0 += 32) {
        int ko = k0 + q * 8;
        short8 af0 = *(short8*)&sx[(m0 + cc) * 72 + ko];
        short8 af1 = *(short8*)&sx[(m0 + 16 + cc) * 72 + ko];
#pragma unroll
        for (int mm = 0; mm < 4; ++mm)
#pragma unroll
            for (int t = 0; t < 4; ++t) {
                // wtb[mm][n][k] == f2b(Wm[k][n]); 16B aligned (ko % 8 == 0)
                short8 bf = *(const short8*)
                    &wtb[mm * 4096 + (t * 16 + cc) * 64 + ko];
                acc[mm][0][t] = __builtin_amdgcn_mfma_f32_16x16x32_bf16(
                    af0, bf, acc[mm][0][t], 0, 0, 0);
                acc[mm][1][t] = __builtin_amdgcn_mfma_f32_16x16x32_bf16(
                    af1, bf, acc[mm][1][t], 0, 0, 0);
            }
    }

    float b1v[2][4], b2v[2][4];
#pragma unroll
    for (int ty = 0; ty < 2; ++ty)
#pragma unroll
        for (int t = 0; t < 4; ++t) {
            b1v[ty][t] = b1[ty * 64 + t * 16 + cc];
            b2v[ty][t] = b2[ty * 64 + t * 16 + cc];
        }

    // C/D layout: col = lane&15, row = quad*4 + reg
#pragma unroll
    for (int s = 0; s < 2; ++s)
#pragma unroll
        for (int reg = 0; reg < 4; ++reg) {
            int rl_ = m0 + s * 16 + q * 4 + reg;
            int r = rowbase + rl_;
            if (r < N) {
                int ty = snt[rl_];
#pragma unroll
                for (int t = 0; t < 4; ++t) {
                    float v1 = (ty ? acc[1][s][t][reg] : acc[0][s][t][reg])
                               + b1v[ty][t];
                    float v2 = (ty ? acc[3][s][t][reg] : acc[2][s][t][reg])
                               + b2v[ty][t];
                    out[(size_t)r * 64 + t * 16 + cc] = v1;
                    h2b[(size_t)r * 64 + t * 16 + cc] = f2b(v2);
                }
            }
        }
}

// ---------------- K2: gather + fused MFMA matvec (32 dsts / block) ----------
// Phase 1 (per wave, 8 dsts in pairs, 8-deep + conditional second chunk --
//   R19/R21's proven form): both dsts' rec batches issued (uniform ->
//   s_load), then both h2b/ef batches (2x lines in flight), ok-predicated
//   accumulate.
// Phase 2: C[32x64] = sa * wtb5 with B fragments read from GLOBAL (L2-hot
//   8KB table, R18 pattern); epilogue adds C + b2f(sHb) to out; plain RMW
//   unless row has cnt>CAP (then atomic, shared with ovf fixup).
__global__ __launch_bounds__(256) void k2_gather_mm(
    const float* __restrict__ ef, const int2* __restrict__ rec,
    const int* __restrict__ cnt32,
    const float* __restrict__ W5, const float* __restrict__ b5,
    const unsigned short* __restrict__ wtb5,
    const int4* __restrict__ ovf, const int* __restrict__ ovfCnt,
    const unsigned short* __restrict__ h2b, float* __restrict__ out,
    int N, int gatherBlocks, int ovfBlocks)
{
    __shared__ __align__(16) unsigned short sa[32 * 136];    // 8.5 KB  A tile
    __shared__ __align__(16) unsigned short sHb[32 * 66];    // 4.125KB accH bf16
    __shared__ int sCnt[32];

    int tid = threadIdx.x;
    int lane = tid & 63;
    int wid = tid >> 6;

    if (blockIdx.x >= (unsigned)gatherBlocks) {
        // ---- overflow fixup: grid-stride waves over ovf list (rare) ----
        int novf = min(*ovfCnt, OVF_CAP);
        int gw = (blockIdx.x - gatherBlocks) * 4 + wid;
        int nw = ovfBlocks * 4;
        for (int ri = gw; ri < novf; ri += nw) {
            int4 o = ovf[ri];
            int s = o.x & 0xFFFFF;
            int t = (unsigned)o.x >> 20;
            float acc = b5[t * 64 + lane] + b2f(h2b[((size_t)s << 6) | lane]);
#pragma unroll
            for (int f = 0; f < 16; ++f)
                acc = fmaf(ef[(size_t)o.y * 16 + f],
                           W5[(t * 16 + f) * 64 + lane], acc);
            unsafeAtomicAdd(&out[(size_t)o.z * 64 + lane], acc);
        }
        return;
    }

    // ---- zero sa tail cols 52..63 and 116..127 (MFMA reads full [0,128)):
    //      32 rows x 6 ushort4 = 192 tasks (R14 lesson: count the width!)
    {
        ushort4 z; z.x = 0; z.y = 0; z.z = 0; z.w = 0;
        if (tid < 192) {
            int row = tid / 6;
            int w6 = tid - row * 6;
            int sp = (w6 < 3) ? (52 + w6 * 4) : (116 + (w6 - 3) * 4);
            *(ushort4*)&sa[row * 136 + sp] = z;
        }
    }

    // ---- phase 1: 8 dsts per wave, processed in pipelined pairs ----
    int myt = (lane < 48) ? (lane >> 4) : (lane - 48);
    unsigned myf = lane & 15;
    bool fl = lane < 48;
    int wbase = blockIdx.x * 32 + wid * 8;

    int cnts[8];
#pragma unroll
    for (int g = 0; g < 8; ++g) {
        int d = wbase + g;
        cnts[g] = (d < N) ? cnt32[d] : 0;
    }
    if (lane == 0) {
#pragma unroll
        for (int g = 0; g < 8; ++g) sCnt[wid * 8 + g] = cnts[g];
    }

#pragma unroll 1
    for (int gp = 0; gp < 8; gp += 2) {
        int dA = wbase + gp, dB = dA + 1;
        int dgA = min(cnts[gp], CAP);
        int dgB = min(cnts[gp + 1], CAP);
        unsigned baseA = (unsigned)(dA < N ? dA : 0) * CAP;
        unsigned baseB = (unsigned)(dB < N ? dB : 0) * CAP;

        // issue both rec batches (wave-uniform -> scalar loads)
        int2 rA[8], rB[8];
#pragma unroll
        for (int j = 0; j < 8; ++j) rA[j] = rec[baseA + j];
#pragma unroll
        for (int j = 0; j < 8; ++j) rB[j] = rec[baseB + j];

        // issue both gather batches (stale slots masked to address 0)
        float hvA[8], evA[8], hvB[8], evB[8];
#pragma unroll
        for (int j = 0; j < 8; ++j) {
            bool ok = j < dgA;
            unsigned s = ok ? ((unsigned)rA[j].x & 0xFFFFFu) : 0u;
            unsigned e = ok ? (unsigned)rA[j].y : 0u;
            hvA[j] = b2f(h2b[((size_t)s << 6) | (unsigned)lane]);
            evA[j] = ef[(e << 4) | myf];
        }
#pragma unroll
        for (int j = 0; j < 8; ++j) {
            bool ok = j < dgB;
            unsigned s = ok ? ((unsigned)rB[j].x & 0xFFFFFu) : 0u;
            unsigned e = ok ? (unsigned)rB[j].y : 0u;
            hvB[j] = b2f(h2b[((size_t)s << 6) | (unsigned)lane]);
            evB[j] = ef[(e << 4) | myf];
        }

        float accHA = 0.f, accSA = 0.f, accHB = 0.f, accSB = 0.f;
#pragma unroll
        for (int j = 0; j < 8; ++j) {
            bool okA = j < dgA;
            int tA = (int)((unsigned)rA[j].x >> 20);
            accHA += okA ? hvA[j] : 0.f;
            float vA = fl ? evA[j] : 1.0f;
            accSA += (okA && tA == myt) ? vA : 0.f;
            bool okB = j < dgB;
            int tB = (int)((unsigned)rB[j].x >> 20);
            accHB += okB ? hvB[j] : 0.f;
            float vB = fl ? evB[j] : 1.0f;
            accSB += (okB && tB == myt) ? vB : 0.f;
        }

        // second chunks (deg > 8): on-demand clamped loads (44% of dsts)
        if (dgA > 8) {
            int2 r2[8];
#pragma unroll
            for (int j = 0; j < 8; ++j)
                r2[j] = rec[baseA + (unsigned)min(8 + j, dgA - 1)];
#pragma unroll
            for (int j = 0; j < 8; ++j) {
                unsigned s = (unsigned)r2[j].x & 0xFFFFFu;
                float hv = b2f(h2b[((size_t)s << 6) | (unsigned)lane]);
                float evv = ef[((unsigned)r2[j].y << 4) | myf];
                int t = (int)((unsigned)r2[j].x >> 20);
                bool ok = (8 + j) < dgA;
                accHA += ok ? hv : 0.f;
                float v = fl ? evv : 1.0f;
                accSA += (ok && t == myt) ? v : 0.f;
            }
        }
        if (dgB > 8) {
            int2 r2[8];
#pragma unroll
            for (int j = 0; j < 8; ++j)
                r2[j] = rec[baseB + (unsigned)min(8 + j, dgB - 1)];
#pragma unroll
            for (int j = 0; j < 8; ++j) {
                unsigned s = (unsigned)r2[j].x & 0xFFFFFu;
                float hv = b2f(h2b[((size_t)s << 6) | (unsigned)lane]);
                float evv = ef[((unsigned)r2[j].y << 4) | myf];
                int t = (int)((unsigned)r2[j].x >> 20);
                bool ok = (8 + j) < dgB;
                accHB += ok ? hv : 0.f;
                float v = fl ? evv : 1.0f;
                accSB += (ok && t == myt) ? v : 0.f;
            }
        }

        int wdA = wid * 8 + gp, wdB = wdA + 1;
        if (lane < 52) {
            unsigned short hiA = f2b(accSA);
            sa[wdA * 136 + lane] = hiA;
            sa[wdA * 136 + 64 + lane] = f2b(accSA - b2f(hiA));
            unsigned short hiB = f2b(accSB);
            sa[wdB * 136 + lane] = hiB;
            sa[wdB * 136 + 64 + lane] = f2b(accSB - b2f(hiB));
        }
        sHb[wdA * 66 + lane] = f2b(accHA);
        sHb[wdB * 66 + lane] = f2b(accHB);
    }
    __syncthreads();

    // ---- phase 2: C[32x64] via MFMA; wave -> row-tile (wid&1),
    //      col-tiles {wid>>1, (wid>>1)+2}; B fragment = global wtb5[ko&63] ----
    int q  = lane >> 4;
    int cc = lane & 15;
    int s  = wid & 1;
    int t0 = wid >> 1;

    f32x4 acc0 = (f32x4){0.f, 0.f, 0.f, 0.f};
    f32x4 acc1 = (f32x4){0.f, 0.f, 0.f, 0.f};
#pragma unroll
    for (int k0 = 0; k0 < 128; k0 += 32) {
        int ko = k0 + q * 8;
        int kb = ko & 63;
        short8 af = *(short8*)&sa[(s * 16 + cc) * 136 + ko];
        short8 bf0 = *(const short8*)&wtb5[(t0 * 16 + cc) * 64 + kb];
        short8 bf1 = *(const short8*)&wtb5[((t0 + 2) * 16 + cc) * 64 + kb];
        acc0 = __builtin_amdgcn_mfma_f32_16x16x32_bf16(af, bf0, acc0, 0, 0, 0);
        acc1 = __builtin_amdgcn_mfma_f32_16x16x32_bf16(af, bf1, acc1, 0, 0, 0);
    }

    // C/D layout: col = lane&15, row = quad*4 + reg
#pragma unroll
    for (int reg = 0; reg < 4; ++reg) {
        int rl = s * 16 + q * 4 + reg;
        int d = blockIdx.x * 32 + rl;
        if (d < N) {
            int c0 = t0 * 16 + cc;
            int c1 = (t0 + 2) * 16 + cc;
            float v0 = acc0[reg] + b2f(sHb[rl * 66 + c0]);
            float v1 = acc1[reg] + b2f(sHb[rl * 66 + c1]);
            float* p0 = &out[(size_t)d * 64 + c0];
            float* p1 = &out[(size_t)d * 64 + c1];
            if (sCnt[rl] > CAP) {      // row shared with ovf fixup -> atomic
                unsafeAtomicAdd(p0, v0);
                unsafeAtomicAdd(p1, v1);
            } else {                   // sole writer -> plain RMW
                *p0 += v0;
                *p1 += v1;
            }
        }
    }
}

extern "C" void kernel_launch(void* const* d_in, const int* in_sizes, int n_in,
                              void* d_out, int out_size, void* d_ws, size_t ws_size,
                              hipStream_t stream) {
    const float* x  = (const float*)d_in[0];
    const float* ef = (const float*)d_in[1];
    const int* nt   = (const int*)d_in[2];
    const int* es   = (const int*)d_in[3];
    const int* ed   = (const int*)d_in[4];
    const int* et   = (const int*)d_in[5];
    const float* W1 = (const float*)d_in[6];
    const float* b1 = (const float*)d_in[7];
    const float* W2 = (const float*)d_in[8];
    const float* b2 = (const float*)d_in[9];
    // d_in[10..13] = W3,b3,W4,b4 dead (score == 1.0)
    const float* W5 = (const float*)d_in[14];
    const float* b5 = (const float*)d_in[15];

    int N = in_sizes[2];
    int M = in_sizes[3];

    char* w = (char*)d_ws;
    size_t off = 0;
    unsigned short* h2b = (unsigned short*)(w + off); off += (size_t)N * 64 * 2;  // 12.8 MB
    off = (off + 255) & ~(size_t)255;
    int2* rec = (int2*)(w + off); off += (size_t)N * CAP * 8;                     // 12.8 MB
    off = (off + 255) & ~(size_t)255;
    int4* ovf = (int4*)(w + off); off += (size_t)OVF_CAP * 16;                    // 0.5 MB
    off = (off + 255) & ~(size_t)255;
    unsigned short* wtb = (unsigned short*)(w + off); off += 4 * 4096 * 2;        // 32 KB
    off = (off + 255) & ~(size_t)255;
    unsigned short* wtb5 = (unsigned short*)(w + off); off += 64 * 64 * 2;        // 8 KB
    off = (off + 255) & ~(size_t)255;
    // zero block: [ovfCnt:1 int][pad->64 B][cnt32: N ints]
    int* ovfCnt = (int*)(w + off);
    int* cnt32  = (int*)(w + off + 64);
    int nZero = 16 + N;                      // ints: ovfCnt+pad + cnt32

    float* out = (float*)d_out;

    int initBlocks = (nZero + 255) / 256;    // 391 (also covers wtb/wtb5)
    k0_init<<<initBlocks, 256, 0, stream>>>(
        ovfCnt, nZero, W1, W2, W5, b5, wtb, wtb5);

    int gemmBlocks    = (N + 127) / 128;     // 782
    int scatterBlocks = (M + 1023) / 1024;   // 782
    int gb1 = 2 * max(gemmBlocks, scatterBlocks);
    k1_fused<<<gb1, 256, 0, stream>>>(
        x, nt, wtb, b1, b2, es, ed, et,
        cnt32, ovfCnt, ovf, rec, out, h2b, N, M);

    int gatherBlocks = (N + 31) / 32;        // 3125
    int ovfBlocks = 32;
    k2_gather_mm<<<gatherBlocks + ovfBlocks, 256, 0, stream>>>(
        ef, rec, cnt32, W5, b5, wtb5, ovf, ovfCnt, h2b, out,
        N, gatherBlocks, ovfBlocks);
}

// Round 17
// 275.592 us; speedup vs baseline: 1.0533x; 1.0249x over previous
//
#include <hip/hip_runtime.h>

// N=100000 nodes, M=800000 edges, F_IN=64, F_E=16, H=64, T_NODE=2, T_EDGE=3.
// score == softmax over singleton axis == 1.0 exactly, so h3/h4/num are dead:
//   out[n] = h1[n] + sum_{e: dst=n} ( h2[src_e] + ef_e . W5[t_e] + b5[t_e] )
//
// R24 = R23 + out-round-trip elimination. K2 was pinned at 94+-1us across
// four variants (phase-1 batching exhausted). Old flow: K1 writes out=h1
// (25.6MB f32), K2 RMWs out (25.6 read + 25.6 write). New flow: K1 writes
// h1 as bf16 to workspace h1b (12.8MB); K2 epilogue PLAIN-STORES
// h1 + C + accH (harness zeroes out pre-launch; atomic only for cnt>CAP
// rows shared with ovf fixup, which sum correctly from 0). K2 FETCH
// 112->99.5MB and the epilogue read->add->write chain is gone; h1b loads
// issue before the MFMA loop to hide under it.
//  K0: zero-init + W1/W2 -> wtb + [W5;b5] -> wtb5.
//  K1: even blocks = slim gemm (h1->h1b bf16, h2->h2b bf16); odd = scatter.
//  K2: gather (8-deep pairs) + fused MFMA matvec, B from wtb5, plain-store.

#define CAP 16
#define OVF_CAP 32768

typedef __attribute__((ext_vector_type(8))) short short8;
typedef __attribute__((ext_vector_type(4))) float f32x4;

__device__ __forceinline__ float b2f(unsigned short u) {
    union { unsigned v; float f; } x; x.v = ((unsigned)u) << 16; return x.f;
}
__device__ __forceinline__ unsigned short f2b(float f) {
    union { float f; unsigned v; } x; x.f = f;
    unsigned u = x.v;
    unsigned r = (u + 0x7FFFu + ((u >> 16) & 1u)) >> 16;
    return (unsigned short)r;
}

// ---------------- K0: zero cnt block + one-shot weight tables ---------------
__global__ __launch_bounds__(256) void k0_init(
    int* __restrict__ zeroBase, int nZero,
    const float* __restrict__ W1, const float* __restrict__ W2,
    const float* __restrict__ W5, const float* __restrict__ b5,
    unsigned short* __restrict__ wtb, unsigned short* __restrict__ wtb5)
{
    int idx = blockIdx.x * 256 + threadIdx.x;
    if (idx < nZero) zeroBase[idx] = 0;
    if (idx < 16384) {
        int mm = idx >> 12;
        int r  = idx & 4095;
        int n  = r >> 6;
        int k  = r & 63;
        const float* src = ((mm < 2) ? W1 : W2) + (mm & 1) * 4096;
        wtb[mm * 4096 + n * 64 + k] = f2b(src[k * 64 + n]);
    }
    if (idx < 4096) {
        int h = idx >> 6;                 // 0..63 output col
        int j = idx & 63;                 // 0..63 K index
        float wv = 0.f;
        if (j < 48)      wv = W5[j * 64 + h];
        else if (j < 51) wv = b5[(j - 48) * 64 + h];
        wtb5[h * 64 + j] = f2b(wv);       // cols 51..63 zero
    }
}

// ---------------- K1: slim gemm (even blocks) || scatter (odd blocks) -------
__global__ __launch_bounds__(256) void k1_fused(
    const float* __restrict__ x, const int* __restrict__ nt,
    const unsigned short* __restrict__ wtb,
    const float* __restrict__ b1, const float* __restrict__ b2,
    const int* __restrict__ esrc, const int* __restrict__ edst,
    const int* __restrict__ etype,
    int* __restrict__ cnt32, int* __restrict__ ovfCnt,
    int4* __restrict__ ovf, int2* __restrict__ rec,
    unsigned short* __restrict__ h1b, unsigned short* __restrict__ h2b,
    int N, int M)
{
    // 72 = 64 + 8 pad: row stride 144 B -> 2-way bank alias (free)
    __shared__ __align__(16) unsigned short sx[128 * 72];     // 18 KB
    __shared__ int snt[128];

    int tid = threadIdx.x;

    if (blockIdx.x & 1) {
        // ---------------- scatter path: 1024 edges/block ---------------------
        int e0 = (blockIdx.x >> 1) * 1024 + tid;
        int dd[4], ssrc[4], tty[4];
        bool v[4];
#pragma unroll
        for (int j = 0; j < 4; ++j) {
            int e = e0 + j * 256;
            v[j] = e < M;
            int ec = v[j] ? e : 0;
            dd[j]   = edst[ec];
            ssrc[j] = esrc[ec];
            tty[j]  = etype[ec];
        }
        int pos[4];
#pragma unroll
        for (int j = 0; j < 4; ++j)
            if (v[j]) pos[j] = atomicAdd(&cnt32[dd[j]], 1);
#pragma unroll
        for (int j = 0; j < 4; ++j) {
            if (!v[j]) continue;
            int packed = ssrc[j] | (tty[j] << 20);
            int e = e0 + j * 256;
            if (pos[j] < CAP) {
                rec[dd[j] * CAP + pos[j]] = make_int2(packed, e);
            } else {
                int slot = atomicAdd(ovfCnt, 1);
                if (slot < OVF_CAP) ovf[slot] = make_int4(packed, e, dd[j], 0);
            }
        }
        return;
    }

    // ---------------- gemm path (B from global wtb) -------------------------
    int rowbase = (blockIdx.x >> 1) * 128;

    if (tid < 128) {
        int r = rowbase + tid;
        snt[tid] = (r < N) ? nt[r] : 0;
    }

    // stage x tile (contiguous rows, no perm)
    int fr = (tid & 15) * 4;
    int ir = tid >> 4;
#pragma unroll
    for (int it = 0; it < 8; ++it) {
        int i = it * 16 + ir;
        int r = rowbase + i;
        float4 v = make_float4(0.f, 0.f, 0.f, 0.f);
        if (r < N) v = *(const float4*)&x[(size_t)r * 64 + fr];
        ushort4 p;
        p.x = f2b(v.x); p.y = f2b(v.y); p.z = f2b(v.z); p.w = f2b(v.w);
        *(ushort4*)&sx[i * 72 + fr] = p;
    }
    __syncthreads();

    int lane = tid & 63;
    int wid  = tid >> 6;
    int q    = lane >> 4;
    int cc   = lane & 15;
    int m0   = wid * 32;

    f32x4 acc[4][2][4];   // [mat][s][t]
#pragma unroll
    for (int mm = 0; mm < 4; ++mm)
#pragma unroll
        for (int s = 0; s < 2; ++s)
#pragma unroll
            for (int t = 0; t < 4; ++t)
                acc[mm][s][t] = (f32x4){0.f, 0.f, 0.f, 0.f};

#pragma unroll
    for (int k0 = 0; k0 < 64; k0 += 32) {
        int ko = k0 + q * 8;
        short8 af0 = *(short8*)&sx[(m0 + cc) * 72 + ko];
        short8 af1 = *(short8*)&sx[(m0 + 16 + cc) * 72 + ko];
#pragma unroll
        for (int mm = 0; mm < 4; ++mm)
#pragma unroll
            for (int t = 0; t < 4; ++t) {
                // wtb[mm][n][k] == f2b(Wm[k][n]); 16B aligned (ko % 8 == 0)
                short8 bf = *(const short8*)
                    &wtb[mm * 4096 + (t * 16 + cc) * 64 + ko];
                acc[mm][0][t] = __builtin_amdgcn_mfma_f32_16x16x32_bf16(
                    af0, bf, acc[mm][0][t], 0, 0, 0);
                acc[mm][1][t] = __builtin_amdgcn_mfma_f32_16x16x32_bf16(
                    af1, bf, acc[mm][1][t], 0, 0, 0);
            }
    }

    float b1v[2][4], b2v[2][4];
#pragma unroll
    for (int ty = 0; ty < 2; ++ty)
#pragma unroll
        for (int t = 0; t < 4; ++t) {
            b1v[ty][t] = b1[ty * 64 + t * 16 + cc];
            b2v[ty][t] = b2[ty * 64 + t * 16 + cc];
        }

    // C/D layout: col = lane&15, row = quad*4 + reg
#pragma unroll
    for (int s = 0; s < 2; ++s)
#pragma unroll
        for (int reg = 0; reg < 4; ++reg) {
            int rl_ = m0 + s * 16 + q * 4 + reg;
            int r = rowbase + rl_;
            if (r < N) {
                int ty = snt[rl_];
#pragma unroll
                for (int t = 0; t < 4; ++t) {
                    float v1 = (ty ? acc[1][s][t][reg] : acc[0][s][t][reg])
                               + b1v[ty][t];
                    float v2 = (ty ? acc[3][s][t][reg] : acc[2][s][t][reg])
                               + b2v[ty][t];
                    h1b[(size_t)r * 64 + t * 16 + cc] = f2b(v1);
                    h2b[(size_t)r * 64 + t * 16 + cc] = f2b(v2);
                }
            }
        }
}

// ---------------- K2: gather + fused MFMA matvec (32 dsts / block) ----------
// Phase 1 (per wave, 8 dsts in pairs, 8-deep + conditional second chunk --
//   proven form): both dsts' rec batches issued (uniform -> s_load), then
//   both h2b/ef batches (2x lines in flight), ok-predicated accumulate.
// Phase 2: C[32x64] = sa * wtb5 (B from L2-hot global table); epilogue
//   PLAIN-STORES h1 + C + accH to out (out pre-zeroed by harness); atomic
//   only for cnt>CAP rows (shared with ovf fixup, sums from 0 correctly).
__global__ __launch_bounds__(256) void k2_gather_mm(
    const float* __restrict__ ef, const int2* __restrict__ rec,
    const int* __restrict__ cnt32,
    const float* __restrict__ W5, const float* __restrict__ b5,
    const unsigned short* __restrict__ wtb5,
    const int4* __restrict__ ovf, const int* __restrict__ ovfCnt,
    const unsigned short* __restrict__ h1b,
    const unsigned short* __restrict__ h2b, float* __restrict__ out,
    int N, int gatherBlocks, int ovfBlocks)
{
    __shared__ __align__(16) unsigned short sa[32 * 136];    // 8.5 KB  A tile
    __shared__ __align__(16) unsigned short sHb[32 * 66];    // 4.125KB accH bf16
    __shared__ int sCnt[32];

    int tid = threadIdx.x;
    int lane = tid & 63;
    int wid = tid >> 6;

    if (blockIdx.x >= (unsigned)gatherBlocks) {
        // ---- overflow fixup: grid-stride waves over ovf list (rare) ----
        int novf = min(*ovfCnt, OVF_CAP);
        int gw = (blockIdx.x - gatherBlocks) * 4 + wid;
        int nw = ovfBlocks * 4;
        for (int ri = gw; ri < novf; ri += nw) {
            int4 o = ovf[ri];
            int s = o.x & 0xFFFFF;
            int t = (unsigned)o.x >> 20;
            float acc = b5[t * 64 + lane] + b2f(h2b[((size_t)s << 6) | lane]);
#pragma unroll
            for (int f = 0; f < 16; ++f)
                acc = fmaf(ef[(size_t)o.y * 16 + f],
                           W5[(t * 16 + f) * 64 + lane], acc);
            unsafeAtomicAdd(&out[(size_t)o.z * 64 + lane], acc);
        }
        return;
    }

    // ---- zero sa tail cols 52..63 and 116..127 (MFMA reads full [0,128)):
    //      32 rows x 6 ushort4 = 192 tasks (R14 lesson: count the width!)
    {
        ushort4 z; z.x = 0; z.y = 0; z.z = 0; z.w = 0;
        if (tid < 192) {
            int row = tid / 6;
            int w6 = tid - row * 6;
            int sp = (w6 < 3) ? (52 + w6 * 4) : (116 + (w6 - 3) * 4);
            *(ushort4*)&sa[row * 136 + sp] = z;
        }
    }

    // ---- phase 1: 8 dsts per wave, processed in pipelined pairs ----
    int myt = (lane < 48) ? (lane >> 4) : (lane - 48);
    unsigned myf = lane & 15;
    bool fl = lane < 48;
    int wbase = blockIdx.x * 32 + wid * 8;

    int cnts[8];
#pragma unroll
    for (int g = 0; g < 8; ++g) {
        int d = wbase + g;
        cnts[g] = (d < N) ? cnt32[d] : 0;
    }
    if (lane == 0) {
#pragma unroll
        for (int g = 0; g < 8; ++g) sCnt[wid * 8 + g] = cnts[g];
    }

#pragma unroll 1
    for (int gp = 0; gp < 8; gp += 2) {
        int dA = wbase + gp, dB = dA + 1;
        int dgA = min(cnts[gp], CAP);
        int dgB = min(cnts[gp + 1], CAP);
        unsigned baseA = (unsigned)(dA < N ? dA : 0) * CAP;
        unsigned baseB = (unsigned)(dB < N ? dB : 0) * CAP;

        // issue both rec batches (wave-uniform -> scalar loads)
        int2 rA[8], rB[8];
#pragma unroll
        for (int j = 0; j < 8; ++j) rA[j] = rec[baseA + j];
#pragma unroll
        for (int j = 0; j < 8; ++j) rB[j] = rec[baseB + j];

        // issue both gather batches (stale slots masked to address 0)
        float hvA[8], evA[8], hvB[8], evB[8];
#pragma unroll
        for (int j = 0; j < 8; ++j) {
            bool ok = j < dgA;
            unsigned s = ok ? ((unsigned)rA[j].x & 0xFFFFFu) : 0u;
            unsigned e = ok ? (unsigned)rA[j].y : 0u;
            hvA[j] = b2f(h2b[((size_t)s << 6) | (unsigned)lane]);
            evA[j] = ef[(e << 4) | myf];
        }
#pragma unroll
        for (int j = 0; j < 8; ++j) {
            bool ok = j < dgB;
            unsigned s = ok ? ((unsigned)rB[j].x & 0xFFFFFu) : 0u;
            unsigned e = ok ? (unsigned)rB[j].y : 0u;
            hvB[j] = b2f(h2b[((size_t)s << 6) | (unsigned)lane]);
            evB[j] = ef[(e << 4) | myf];
        }

        float accHA = 0.f, accSA = 0.f, accHB = 0.f, accSB = 0.f;
#pragma unroll
        for (int j = 0; j < 8; ++j) {
            bool okA = j < dgA;
            int tA = (int)((unsigned)rA[j].x >> 20);
            accHA += okA ? hvA[j] : 0.f;
            float vA = fl ? evA[j] : 1.0f;
            accSA += (okA && tA == myt) ? vA : 0.f;
            bool okB = j < dgB;
            int tB = (int)((unsigned)rB[j].x >> 20);
            accHB += okB ? hvB[j] : 0.f;
            float vB = fl ? evB[j] : 1.0f;
            accSB += (okB && tB == myt) ? vB : 0.f;
        }

        // second chunks (deg > 8): on-demand clamped loads (44% of dsts)
        if (dgA > 8) {
            int2 r2[8];
#pragma unroll
            for (int j = 0; j < 8; ++j)
                r2[j] = rec[baseA + (unsigned)min(8 + j, dgA - 1)];
#pragma unroll
            for (int j = 0; j < 8; ++j) {
                unsigned s = (unsigned)r2[j].x & 0xFFFFFu;
                float hv = b2f(h2b[((size_t)s << 6) | (unsigned)lane]);
                float evv = ef[((unsigned)r2[j].y << 4) | myf];
                int t = (int)((unsigned)r2[j].x >> 20);
                bool ok = (8 + j) < dgA;
                accHA += ok ? hv : 0.f;
                float v = fl ? evv : 1.0f;
                accSA += (ok && t == myt) ? v : 0.f;
            }
        }
        if (dgB > 8) {
            int2 r2[8];
#pragma unroll
            for (int j = 0; j < 8; ++j)
                r2[j] = rec[baseB + (unsigned)min(8 + j, dgB - 1)];
#pragma unroll
            for (int j = 0; j < 8; ++j) {
                unsigned s = (unsigned)r2[j].x & 0xFFFFFu;
                float hv = b2f(h2b[((size_t)s << 6) | (unsigned)lane]);
                float evv = ef[((unsigned)r2[j].y << 4) | myf];
                int t = (int)((unsigned)r2[j].x >> 20);
                bool ok = (8 + j) < dgB;
                accHB += ok ? hv : 0.f;
                float v = fl ? evv : 1.0f;
                accSB += (ok && t == myt) ? v : 0.f;
            }
        }

        int wdA = wid * 8 + gp, wdB = wdA + 1;
        if (lane < 52) {
            unsigned short hiA = f2b(accSA);
            sa[wdA * 136 + lane] = hiA;
            sa[wdA * 136 + 64 + lane] = f2b(accSA - b2f(hiA));
            unsigned short hiB = f2b(accSB);
            sa[wdB * 136 + lane] = hiB;
            sa[wdB * 136 + 64 + lane] = f2b(accSB - b2f(hiB));
        }
        sHb[wdA * 66 + lane] = f2b(accHA);
        sHb[wdB * 66 + lane] = f2b(accHB);
    }
    __syncthreads();

    // ---- phase 2: C[32x64] via MFMA; wave -> row-tile (wid&1),
    //      col-tiles {wid>>1, (wid>>1)+2}; B fragment = global wtb5[ko&63] ----
    int q  = lane >> 4;
    int cc = lane & 15;
    int s  = wid & 1;
    int t0 = wid >> 1;

    // prefetch this wave's h1 epilogue values (hide under MFMA + sa reads)
    float h1v[4][2];
#pragma unroll
    for (int reg = 0; reg < 4; ++reg) {
        int rl = s * 16 + q * 4 + reg;
        int d = blockIdx.x * 32 + rl;
        unsigned dc = (unsigned)((d < N) ? d : 0);
        h1v[reg][0] = b2f(h1b[(size_t)dc * 64 + t0 * 16 + cc]);
        h1v[reg][1] = b2f(h1b[(size_t)dc * 64 + (t0 + 2) * 16 + cc]);
    }

    f32x4 acc0 = (f32x4){0.f, 0.f, 0.f, 0.f};
    f32x4 acc1 = (f32x4){0.f, 0.f, 0.f, 0.f};
#pragma unroll
    for (int k0 = 0; k0 < 128; k0 += 32) {
        int ko = k0 + q * 8;
        int kb = ko & 63;
        short8 af = *(short8*)&sa[(s * 16 + cc) * 136 + ko];
        short8 bf0 = *(const short8*)&wtb5[(t0 * 16 + cc) * 64 + kb];
        short8 bf1 = *(const short8*)&wtb5[((t0 + 2) * 16 + cc) * 64 + kb];
        acc0 = __builtin_amdgcn_mfma_f32_16x16x32_bf16(af, bf0, acc0, 0, 0, 0);
        acc1 = __builtin_amdgcn_mfma_f32_16x16x32_bf16(af, bf1, acc1, 0, 0, 0);
    }

    // C/D layout: col = lane&15, row = quad*4 + reg
#pragma unroll
    for (int reg = 0; reg < 4; ++reg) {
        int rl = s * 16 + q * 4 + reg;
        int d = blockIdx.x * 32 + rl;
        if (d < N) {
            int c0 = t0 * 16 + cc;
            int c1 = (t0 + 2) * 16 + cc;
            float v0 = acc0[reg] + b2f(sHb[rl * 66 + c0]) + h1v[reg][0];
            float v1 = acc1[reg] + b2f(sHb[rl * 66 + c1]) + h1v[reg][1];
            float* p0 = &out[(size_t)d * 64 + c0];
            float* p1 = &out[(size_t)d * 64 + c1];
            if (sCnt[rl] > CAP) {      // row shared with ovf fixup -> atomic
                unsafeAtomicAdd(p0, v0);
                unsafeAtomicAdd(p1, v1);
            } else {                   // sole writer -> plain store
                *p0 = v0;
                *p1 = v1;
            }
        }
    }
}

extern "C" void kernel_launch(void* const* d_in, const int* in_sizes, int n_in,
                              void* d_out, int out_size, void* d_ws, size_t ws_size,
                              hipStream_t stream) {
    const float* x  = (const float*)d_in[0];
    const float* ef = (const float*)d_in[1];
    const int* nt   = (const int*)d_in[2];
    const int* es   = (const int*)d_in[3];
    const int* ed   = (const int*)d_in[4];
    const int* et   = (const int*)d_in[5];
    const float* W1 = (const float*)d_in[6];
    const float* b1 = (const float*)d_in[7];
    const float* W2 = (const float*)d_in[8];
    const float* b2 = (const float*)d_in[9];
    // d_in[10..13] = W3,b3,W4,b4 dead (score == 1.0)
    const float* W5 = (const float*)d_in[14];
    const float* b5 = (const float*)d_in[15];

    int N = in_sizes[2];
    int M = in_sizes[3];

    char* w = (char*)d_ws;
    size_t off = 0;
    unsigned short* h2b = (unsigned short*)(w + off); off += (size_t)N * 64 * 2;  // 12.8 MB
    off = (off + 255) & ~(size_t)255;
    unsigned short* h1b = (unsigned short*)(w + off); off += (size_t)N * 64 * 2;  // 12.8 MB
    off = (off + 255) & ~(size_t)255;
    int2* rec = (int2*)(w + off); off += (size_t)N * CAP * 8;                     // 12.8 MB
    off = (off + 255) & ~(size_t)255;
    int4* ovf = (int4*)(w + off); off += (size_t)OVF_CAP * 16;                    // 0.5 MB
    off = (off + 255) & ~(size_t)255;
    unsigned short* wtb = (unsigned short*)(w + off); off += 4 * 4096 * 2;        // 32 KB
    off = (off + 255) & ~(size_t)255;
    unsigned short* wtb5 = (unsigned short*)(w + off); off += 64 * 64 * 2;        // 8 KB
    off = (off + 255) & ~(size_t)255;
    // zero block: [ovfCnt:1 int][pad->64 B][cnt32: N ints]
    int* ovfCnt = (int*)(w + off);
    int* cnt32  = (int*)(w + off + 64);
    int nZero = 16 + N;                      // ints: ovfCnt+pad + cnt32

    float* out = (float*)d_out;

    int initBlocks = (nZero + 255) / 256;    // 391 (also covers wtb/wtb5)
    k0_init<<<initBlocks, 256, 0, stream>>>(
        ovfCnt, nZero, W1, W2, W5, b5, wtb, wtb5);

    int gemmBlocks    = (N + 127) / 128;     // 782
    int scatterBlocks = (M + 1023) / 1024;   // 782
    int gb1 = 2 * max(gemmBlocks, scatterBlocks);
    k1_fused<<<gb1, 256, 0, stream>>>(
        x, nt, wtb, b1, b2, es, ed, et,
        cnt32, ovfCnt, ovf, rec, h1b, h2b, N, M);

    int gatherBlocks = (N + 31) / 32;        // 3125
    int ovfBlocks = 32;
    k2_gather_mm<<<gatherBlocks + ovfBlocks, 256, 0, stream>>>(
        ef, rec, cnt32, W5, b5, wtb5, ovf, ovfCnt, h1b, h2b, out,
        N, gatherBlocks, ovfBlocks);
}